// Round 13
// baseline (2702.966 us; speedup 1.0000x reference)
//
#include <hip/hip_runtime.h>
#include <hip/hip_bf16.h>
#include <type_traits>

#define N_NODES 100000
#define N_EDGES 1600000
#define SLICE_N 12500   // N_NODES / 8 dst-slices for XCD-local fill
#define PCAP    220000  // per-slice partition capacity (mean 200k, std ~420)

typedef float f32x4 __attribute__((ext_vector_type(4)));
typedef _Float16 f16x8 __attribute__((ext_vector_type(8)));
typedef _Float16 f16x4 __attribute__((ext_vector_type(4)));

// ---------------- degree count (in-degree at dst) ----------------
__global__ void count_deg_kernel(const int* __restrict__ dst, int* __restrict__ deg) {
    int i = blockIdx.x * blockDim.x + threadIdx.x;
    if (i < N_EDGES) atomicAdd(&deg[dst[i]], 1);
}

__global__ void dinv_kernel(const int* __restrict__ deg, float* __restrict__ dinv) {
    int i = blockIdx.x * blockDim.x + threadIdx.x;
    if (i < N_NODES) dinv[i] = 1.0f / sqrtf((float)deg[i] + 1.0f);
}

// ---------------- CSR build: block scan -> partial scan -> add ----------------
__global__ void block_scan_kernel(const int* __restrict__ deg, int* __restrict__ rowptr,
                                  int* __restrict__ bsums) {
    __shared__ int s[256];
    int i = blockIdx.x * 256 + threadIdx.x;
    int v = (i < N_NODES) ? deg[i] : 0;
    s[threadIdx.x] = v;
    __syncthreads();
    #pragma unroll
    for (int off = 1; off < 256; off <<= 1) {
        int t = (threadIdx.x >= off) ? s[threadIdx.x - off] : 0;
        __syncthreads();
        s[threadIdx.x] += t;
        __syncthreads();
    }
    if (i < N_NODES) rowptr[i] = s[threadIdx.x] - v;   // exclusive within block
    if (threadIdx.x == 255) bsums[blockIdx.x] = s[255];
}

__global__ void scan_bsums_kernel(int* __restrict__ bsums, int nB) {
    __shared__ int s[512];
    int tid = threadIdx.x;
    int v = (tid < nB) ? bsums[tid] : 0;
    s[tid] = v;
    __syncthreads();
    #pragma unroll
    for (int off = 1; off < 512; off <<= 1) {
        int t = (tid >= off) ? s[tid - off] : 0;
        __syncthreads();
        s[tid] += t;
        __syncthreads();
    }
    if (tid < nB) bsums[tid] = s[tid] - v;             // exclusive
}

__global__ void add_offsets_kernel(int* __restrict__ rowptr, const int* __restrict__ bsums,
                                   int* __restrict__ cursor) {
    int i = blockIdx.x * 256 + threadIdx.x;
    if (i < N_NODES) {
        int r = rowptr[i] + bsums[blockIdx.x];
        rowptr[i] = r;
        cursor[i] = r;
    }
    if (i == 0) rowptr[N_NODES] = N_EDGES;
}

// ---- phase A: partition edges into 8 per-slice regions (wave-aggregated append) ----
__global__ __launch_bounds__(256) void part_kernel(const int* __restrict__ esrc,
                                                   const int* __restrict__ edst,
                                                   int* __restrict__ scursor,
                                                   int2* __restrict__ epart) {
    const int base = blockIdx.x * 2048 + threadIdx.x;
    const int lane = threadIdx.x & 63;
    #pragma unroll
    for (int i = 0; i < 8; ++i) {
        int e = base + i * 256;
        bool valid = e < N_EDGES;
        int d = valid ? edst[e] : 0;
        int s = valid ? esrc[e] : 0;
        int sl = d / SLICE_N;   // 0..7
        #pragma unroll
        for (int t = 0; t < 8; ++t) {
            bool pred = valid && (sl == t);
            unsigned long long mask = __ballot(pred);
            if (mask == 0) continue;                       // wave-uniform
            int cnt = __popcll(mask);
            int leader = __ffsll((unsigned long long)mask) - 1;
            int prefix = __popcll(mask & ((1ull << lane) - 1ull));
            int wbase = 0;
            if (lane == leader) wbase = atomicAdd(&scursor[t], cnt);
            wbase = __shfl(wbase, leader);
            if (pred) epart[(size_t)t * PCAP + wbase + prefix] = make_int2(s, d);
        }
    }
}

// ---- phase B: per-slice fill; reads its own partition, scatters into L2-resident window ----
__global__ __launch_bounds__(256) void fill2_kernel(const int2* __restrict__ epart,
                                                    const int* __restrict__ scount,
                                                    int* __restrict__ cursor,
                                                    int* __restrict__ esorted) {
    const int sl = blockIdx.x & 7;
    const int chunk = blockIdx.x >> 3;
    const int count = scount[sl];
    const int base = chunk * 2048 + threadIdx.x;
    #pragma unroll
    for (int i = 0; i < 8; ++i) {
        int idx = base + i * 256;
        if (idx < count) {
            int2 p = epart[(size_t)sl * PCAP + idx];
            int pos = atomicAdd(&cursor[p.y], 1);
            esorted[pos] = p.x;
        }
    }
}

// ---------------- W[K][M] row-major -> Wt[M][K] transposed fp16 ----------------
__global__ void wconv_kernel(const float* __restrict__ W, int K, int M,
                             _Float16* __restrict__ Wt) {
    int i = blockIdx.x * 256 + threadIdx.x;
    if (i >= K * M) return;
    int k = i / M, col = i % M;
    Wt[col * K + k] = (_Float16)W[i];
}

// ---------------- LDS-free fp16 MFMA GEMM, FR=1 (64 rows/block), 2-deep pipeline ----------------
// C[r,:] = fp16( (A @ W)[r,:] * dinv[r] ); A is fp32 (converted in-register) or fp16.
template<int K, int M, typename AT>
__global__ __launch_bounds__(256) void mfma_gemm_f16(const AT* __restrict__ A,
                                                     const _Float16* __restrict__ Bt,
                                                     const float* __restrict__ dinv,
                                                     _Float16* __restrict__ C) {
    constexpr bool AF32 = std::is_same<AT, float>::value;
    constexpr int FC = M / 16;
    constexpr int NIT = K / 32;
    const int tid = threadIdx.x;
    const int wave = tid >> 6, lane = tid & 63;
    const int row0 = blockIdx.x * 64;
    const int r0 = wave * 16;
    const int l15 = lane & 15, kof = (lane >> 4) * 8;

    f32x4 acc[FC] = {};
    int g0 = row0 + r0 + l15;
    const int gr = (g0 < N_NODES) ? g0 : N_NODES - 1;

    f32x4 a_cur32[2], a_nxt32[2];
    f16x8 a_cur16, a_nxt16;
    f16x8 b_cur[FC], b_nxt[FC];

    {
        const AT* ap = A + (size_t)gr * K + kof;
        if constexpr (AF32) {
            a_cur32[0] = *(const f32x4*)ap;
            a_cur32[1] = *(const f32x4*)(ap + 4);
        } else {
            a_cur16 = *(const f16x8*)ap;
        }
    }
    #pragma unroll
    for (int c = 0; c < FC; ++c)
        b_cur[c] = *(const f16x8*)(Bt + (size_t)(c * 16 + l15) * K + kof);

    #pragma unroll
    for (int it = 0; it < NIT; ++it) {
        const int k1 = (it + 1) * 32;
        if (it + 1 < NIT) {
            const AT* ap = A + (size_t)gr * K + k1 + kof;
            if constexpr (AF32) {
                a_nxt32[0] = *(const f32x4*)ap;
                a_nxt32[1] = *(const f32x4*)(ap + 4);
            } else {
                a_nxt16 = *(const f16x8*)ap;
            }
            #pragma unroll
            for (int c = 0; c < FC; ++c)
                b_nxt[c] = *(const f16x8*)(Bt + (size_t)(c * 16 + l15) * K + k1 + kof);
        }
        f16x8 af;
        if constexpr (AF32) {
            #pragma unroll
            for (int j = 0; j < 4; ++j) {
                af[j] = (_Float16)a_cur32[0][j];
                af[4 + j] = (_Float16)a_cur32[1][j];
            }
        } else {
            af = a_cur16;
        }
        #pragma unroll
        for (int c = 0; c < FC; ++c)
            acc[c] = __builtin_amdgcn_mfma_f32_16x16x32_f16(af, b_cur[c], acc[c], 0, 0, 0);
        if (it + 1 < NIT) {
            if constexpr (AF32) {
                a_cur32[0] = a_nxt32[0];
                a_cur32[1] = a_nxt32[1];
            } else {
                a_cur16 = a_nxt16;
            }
            #pragma unroll
            for (int c = 0; c < FC; ++c) b_cur[c] = b_nxt[c];
        }
    }

    // ---- epilogue: C/D frag layout col=lane&15, row=(lane>>4)*4+reg; fp16 store ----
    #pragma unroll
    for (int j = 0; j < 4; ++j) {
        int g = row0 + r0 + (lane >> 4) * 4 + j;
        if (g >= N_NODES) continue;
        float s = dinv[g];
        #pragma unroll
        for (int c = 0; c < FC; ++c)
            C[(size_t)g * M + c * 16 + l15] = (_Float16)(acc[c][j] * s);
    }
}

// ---------------- CSR gather: out16[n] = fp16( dinv[n]*(sum hs[src] + hs[n]) + b ) ----------------
template<int M, int G>
__global__ __launch_bounds__(256) void gather_kernel(const int* __restrict__ rowptr,
                                                     const int* __restrict__ esorted,
                                                     const float* __restrict__ dinv,
                                                     const f16x8* __restrict__ hs,
                                                     const float* __restrict__ bias,
                                                     _Float16* __restrict__ out) {
    static_assert(M == 8 * G, "layout");
    constexpr int R = M / 8;   // f16x8 chunks per row
    int gid = blockIdx.x * blockDim.x + threadIdx.x;
    int node = gid / G;
    int lane = gid % G;
    if (node >= N_NODES) return;
    int beg = rowptr[node], end = rowptr[node + 1];
    float dn = dinv[node];
    f16x8 hv = hs[(size_t)node * R + lane];   // self term
    float acc[8];
    #pragma unroll
    for (int d = 0; d < 8; ++d) acc[d] = (float)hv[d];
    int j = beg;
    for (; j + 8 <= end; j += 8) {
        int s[8];
        f16x8 v[8];
        #pragma unroll
        for (int k = 0; k < 8; ++k) s[k] = esorted[j + k];
        #pragma unroll
        for (int k = 0; k < 8; ++k) v[k] = hs[(size_t)s[k] * R + lane];
        #pragma unroll
        for (int k = 0; k < 8; ++k)
            #pragma unroll
            for (int d = 0; d < 8; ++d) acc[d] += (float)v[k][d];
    }
    for (; j < end; ++j) {
        f16x8 v = hs[(size_t)esorted[j] * R + lane];
        #pragma unroll
        for (int d = 0; d < 8; ++d) acc[d] += (float)v[d];
    }
    const float* bp = bias + lane * 8;
    f16x8 o;
    #pragma unroll
    for (int d = 0; d < 8; ++d) o[d] = (_Float16)(acc[d] * dn + bp[d]);
    *((f16x8*)out + (size_t)node * R + lane) = o;
}

// ---------------- layer-2 gather fused with log_softmax (M=32, G=8), fp32 out ----------------
__global__ __launch_bounds__(256) void gather_lsm_kernel(const int* __restrict__ rowptr,
                                                         const int* __restrict__ esorted,
                                                         const float* __restrict__ dinv,
                                                         const f16x4* __restrict__ hs,
                                                         const float* __restrict__ bias,
                                                         float* __restrict__ out) {
    constexpr int R = 8;   // f16x4 chunks per 32-wide row
    int gid = blockIdx.x * blockDim.x + threadIdx.x;
    int node = gid / 8;
    int lane = gid % 8;
    if (node >= N_NODES) return;
    int beg = rowptr[node], end = rowptr[node + 1];
    float dn = dinv[node];
    f16x4 hv = hs[(size_t)node * R + lane];
    float4 acc = make_float4((float)hv[0], (float)hv[1], (float)hv[2], (float)hv[3]);
    int j = beg;
    for (; j + 4 <= end; j += 4) {
        int s0 = esorted[j + 0];
        int s1 = esorted[j + 1];
        int s2 = esorted[j + 2];
        int s3 = esorted[j + 3];
        f16x4 v0 = hs[(size_t)s0 * R + lane];
        f16x4 v1 = hs[(size_t)s1 * R + lane];
        f16x4 v2 = hs[(size_t)s2 * R + lane];
        f16x4 v3 = hs[(size_t)s3 * R + lane];
        acc.x += ((float)v0[0] + (float)v1[0]) + ((float)v2[0] + (float)v3[0]);
        acc.y += ((float)v0[1] + (float)v1[1]) + ((float)v2[1] + (float)v3[1]);
        acc.z += ((float)v0[2] + (float)v1[2]) + ((float)v2[2] + (float)v3[2]);
        acc.w += ((float)v0[3] + (float)v1[3]) + ((float)v2[3] + (float)v3[3]);
    }
    for (; j < end; ++j) {
        f16x4 v = hs[(size_t)esorted[j] * R + lane];
        acc.x += (float)v[0];
        acc.y += (float)v[1];
        acc.z += (float)v[2];
        acc.w += (float)v[3];
    }
    float4 b = ((const float4*)bias)[lane];
    float4 o;
    o.x = acc.x * dn + b.x;
    o.y = acc.y * dn + b.y;
    o.z = acc.z * dn + b.z;
    o.w = acc.w * dn + b.w;
    // log_softmax over the 32-class row (8 lanes x 4)
    float m = fmaxf(fmaxf(o.x, o.y), fmaxf(o.z, o.w));
    m = fmaxf(m, __shfl_xor(m, 1, 8));
    m = fmaxf(m, __shfl_xor(m, 2, 8));
    m = fmaxf(m, __shfl_xor(m, 4, 8));
    float s = expf(o.x - m) + expf(o.y - m) + expf(o.z - m) + expf(o.w - m);
    s += __shfl_xor(s, 1, 8);
    s += __shfl_xor(s, 2, 8);
    s += __shfl_xor(s, 4, 8);
    float ls = m + logf(s);
    float4 r;
    r.x = o.x - ls; r.y = o.y - ls; r.z = o.z - ls; r.w = o.w - ls;
    ((float4*)out)[(size_t)node * R + lane] = r;
}

extern "C" void kernel_launch(void* const* d_in, const int* in_sizes, int n_in,
                              void* d_out, int out_size, void* d_ws, size_t ws_size,
                              hipStream_t stream) {
    const float* x  = (const float*)d_in[0];
    const int*   ei = (const int*)d_in[1];     // [2, E] int32
    const float* W0 = (const float*)d_in[2];
    const float* b0 = (const float*)d_in[3];
    const float* W1 = (const float*)d_in[4];
    const float* b1 = (const float*)d_in[5];
    const float* W2 = (const float*)d_in[6];
    const float* b2 = (const float*)d_in[7];
    float* out = (float*)d_out;

    char* ws = (char*)d_ws;
    float* dinv    = (float*)(ws + 0);                  // 400 KB
    int*   deg     = (int*)  (ws + (512 << 10));        // 400 KB (reused as cursor)
    int*   rowptr  = (int*)  (ws + (1 << 20));          // 400 KB + 4
    int*   bsums   = (int*)  (ws + (1536 << 10));       // ~1.6 KB
    int*   scursor = (int*)  (ws + (1540 << 10));       // 32 B (slice cursors / counts)
    int*   esorted = (int*)  (ws + (2 << 20));          // 6.4 MB
    _Float16* Wt0  = (_Float16*)(ws + 8847360);             // 64 KB
    _Float16* Wt1  = (_Float16*)(ws + 8847360 + 65536);     // 32 KB
    _Float16* Wt2  = (_Float16*)(ws + 8847360 + 98304);     // 8 KB
    _Float16* hs     = (_Float16*)(ws + 9437184);              // 25.6 MB (fp16 h*dinv)
    _Float16* bufB16 = (_Float16*)(ws + 9437184 + 51200000);   // 25.6 MB (fp16 activations)
    int2*  epart   = (int2*) (ws + 86237184);           // 14.08 MB (8 x PCAP x int2)
    const int* esrc = ei;
    const int* edst = ei + N_EDGES;

    const int NB = (N_NODES + 255) / 256;   // 391
    const int ECH = (N_EDGES + 2047) / 2048;   // 782

    // ---- degree / dinv / CSR (two-phase partitioned fill) / W pre-convert ----
    (void)hipMemsetAsync(deg, 0, N_NODES * sizeof(int), stream);
    (void)hipMemsetAsync(scursor, 0, 8 * sizeof(int), stream);
    count_deg_kernel<<<N_EDGES / 256, 256, 0, stream>>>(edst, deg);
    dinv_kernel<<<NB, 256, 0, stream>>>(deg, dinv);
    block_scan_kernel<<<NB, 256, 0, stream>>>(deg, rowptr, bsums);
    scan_bsums_kernel<<<1, 512, 0, stream>>>(bsums, NB);
    add_offsets_kernel<<<NB, 256, 0, stream>>>(rowptr, bsums, deg /*cursor*/);
    part_kernel<<<ECH, 256, 0, stream>>>(esrc, edst, scursor, epart);
    fill2_kernel<<<128 * 8, 256, 0, stream>>>(epart, scursor, deg /*cursor*/, esorted);
    wconv_kernel<<<(256 * 128 + 255) / 256, 256, 0, stream>>>(W0, 256, 128, Wt0);
    wconv_kernel<<<(128 * 128 + 255) / 256, 256, 0, stream>>>(W1, 128, 128, Wt1);
    wconv_kernel<<<(128 * 32 + 255) / 256, 256, 0, stream>>>(W2, 128, 32, Wt2);

    const int RB64 = (N_NODES + 63) / 64;   // 1563

    // ---- layer 0: hs = fp16((x @ W0) * dinv) ; aggregate -> bufB16 (fp16) ----
    mfma_gemm_f16<256, 128, float><<<RB64, 256, 0, stream>>>(x, Wt0, dinv, hs);
    gather_kernel<128, 16><<<(N_NODES * 16 + 255) / 256, 256, 0, stream>>>(
        rowptr, esorted, dinv, (const f16x8*)hs, b0, bufB16);

    // ---- layer 1 (A in fp16) ----
    mfma_gemm_f16<128, 128, _Float16><<<RB64, 256, 0, stream>>>(bufB16, Wt1, dinv, hs);
    gather_kernel<128, 16><<<(N_NODES * 16 + 255) / 256, 256, 0, stream>>>(
        rowptr, esorted, dinv, (const f16x8*)hs, b1, bufB16);

    // ---- layer 2 (A in fp16): gather fused with log_softmax, writes d_out ----
    mfma_gemm_f16<128, 32, _Float16><<<RB64, 256, 0, stream>>>(bufB16, Wt2, dinv, hs);
    gather_lsm_kernel<<<(N_NODES * 8 + 255) / 256, 256, 0, stream>>>(
        rowptr, esorted, dinv, (const f16x4*)hs, b2, out);
}

// Round 14
// 434.718 us; speedup vs baseline: 6.2177x; 6.2177x over previous
//
#include <hip/hip_runtime.h>
#include <hip/hip_bf16.h>
#include <type_traits>

#define N_NODES 100000
#define N_EDGES 1600000
#define SLICE_N 12500   // N_NODES / 8 dst-slices for XCD-local fill
#define NBLK    782     // ceil(N_EDGES / 2048)

typedef float f32x4 __attribute__((ext_vector_type(4)));
typedef _Float16 f16x8 __attribute__((ext_vector_type(8)));
typedef _Float16 f16x4 __attribute__((ext_vector_type(4)));

// ---------------- degree count (in-degree at dst) ----------------
__global__ void count_deg_kernel(const int* __restrict__ dst, int* __restrict__ deg) {
    int i = blockIdx.x * blockDim.x + threadIdx.x;
    if (i < N_EDGES) atomicAdd(&deg[dst[i]], 1);
}

__global__ void dinv_kernel(const int* __restrict__ deg, float* __restrict__ dinv) {
    int i = blockIdx.x * blockDim.x + threadIdx.x;
    if (i < N_NODES) dinv[i] = 1.0f / sqrtf((float)deg[i] + 1.0f);
}

// ---------------- CSR build: block scan -> partial scan -> add ----------------
__global__ void block_scan_kernel(const int* __restrict__ deg, int* __restrict__ rowptr,
                                  int* __restrict__ bsums) {
    __shared__ int s[256];
    int i = blockIdx.x * 256 + threadIdx.x;
    int v = (i < N_NODES) ? deg[i] : 0;
    s[threadIdx.x] = v;
    __syncthreads();
    #pragma unroll
    for (int off = 1; off < 256; off <<= 1) {
        int t = (threadIdx.x >= off) ? s[threadIdx.x - off] : 0;
        __syncthreads();
        s[threadIdx.x] += t;
        __syncthreads();
    }
    if (i < N_NODES) rowptr[i] = s[threadIdx.x] - v;   // exclusive within block
    if (threadIdx.x == 255) bsums[blockIdx.x] = s[255];
}

__global__ void scan_bsums_kernel(int* __restrict__ bsums, int nB) {
    __shared__ int s[512];
    int tid = threadIdx.x;
    int v = (tid < nB) ? bsums[tid] : 0;
    s[tid] = v;
    __syncthreads();
    #pragma unroll
    for (int off = 1; off < 512; off <<= 1) {
        int t = (tid >= off) ? s[tid - off] : 0;
        __syncthreads();
        s[tid] += t;
        __syncthreads();
    }
    if (tid < nB) bsums[tid] = s[tid] - v;             // exclusive
}

__global__ void add_offsets_kernel(int* __restrict__ rowptr, const int* __restrict__ bsums,
                                   int* __restrict__ cursor) {
    int i = blockIdx.x * 256 + threadIdx.x;
    if (i < N_NODES) {
        int r = rowptr[i] + bsums[blockIdx.x];
        rowptr[i] = r;
        cursor[i] = r;
    }
    if (i == 0) rowptr[N_NODES] = N_EDGES;
}

// ---- phase A: per-block slice-sort into private epart segment (NO global atomics) ----
__global__ __launch_bounds__(256) void part_kernel(const int* __restrict__ esrc,
                                                   const int* __restrict__ edst,
                                                   int2* __restrict__ epart,
                                                   int* __restrict__ bcnt) {
    __shared__ int hist[8];
    __shared__ int scan[8];
    __shared__ int2 stage[2048];
    const int blk = blockIdx.x;
    const int base = blk * 2048;
    int sl[8], lpos[8], ss[8], dd[8];
    if (threadIdx.x < 8) hist[threadIdx.x] = 0;
    __syncthreads();
    #pragma unroll
    for (int i = 0; i < 8; ++i) {
        int e = base + i * 256 + threadIdx.x;
        if (e < N_EDGES) {
            dd[i] = edst[e];
            ss[i] = esrc[e];
            sl[i] = dd[i] / SLICE_N;
            lpos[i] = atomicAdd(&hist[sl[i]], 1);   // LDS atomic
        } else {
            sl[i] = -1;
        }
    }
    __syncthreads();
    if (threadIdx.x == 0) {
        int acc = 0;
        #pragma unroll
        for (int t = 0; t < 8; ++t) { scan[t] = acc; acc += hist[t]; }
    }
    if (threadIdx.x < 8) bcnt[blk * 8 + threadIdx.x] = hist[threadIdx.x];
    __syncthreads();
    #pragma unroll
    for (int i = 0; i < 8; ++i)
        if (sl[i] >= 0) stage[scan[sl[i]] + lpos[i]] = make_int2(ss[i], dd[i]);
    __syncthreads();
    const int total = scan[7] + hist[7];
    #pragma unroll
    for (int i = 0; i < 8; ++i) {
        int idx = i * 256 + threadIdx.x;
        if (idx < total) epart[(size_t)blk * 2048 + idx] = stage[idx];
    }
}

// ---- phase B: per-slice fill from slice-sorted segments into L2-resident window ----
__global__ __launch_bounds__(256) void fill3_kernel(const int2* __restrict__ epart,
                                                    const int* __restrict__ bcnt,
                                                    int* __restrict__ cursor,
                                                    int* __restrict__ esorted) {
    const int sl = blockIdx.x & 7;
    const int chunk = blockIdx.x >> 3;
    #pragma unroll
    for (int q = 0; q < 8; ++q) {
        const int sb = chunk * 8 + q;
        if (sb < NBLK) {
            int off = 0, len = 0;
            #pragma unroll
            for (int t = 0; t < 8; ++t) {
                int c = bcnt[sb * 8 + t];
                if (t < sl) off += c;
                if (t == sl) len = c;
            }
            const int2* seg = epart + (size_t)sb * 2048 + off;
            for (int idx = threadIdx.x; idx < len; idx += 256) {
                int2 p = seg[idx];
                int pos = atomicAdd(&cursor[p.y], 1);
                esorted[pos] = p.x;
            }
        }
    }
}

// ---------------- W[K][M] row-major -> Wt[M][K] transposed fp16 ----------------
__global__ void wconv_kernel(const float* __restrict__ W, int K, int M,
                             _Float16* __restrict__ Wt) {
    int i = blockIdx.x * 256 + threadIdx.x;
    if (i >= K * M) return;
    int k = i / M, col = i % M;
    Wt[col * K + k] = (_Float16)W[i];
}

// ---------------- LDS-free fp16 MFMA GEMM, FR=1 (64 rows/block), 2-deep pipeline ----------------
// C[r,:] = fp16( (A @ W)[r,:] * dinv[r] ); A is fp32 (converted in-register) or fp16.
template<int K, int M, typename AT>
__global__ __launch_bounds__(256) void mfma_gemm_f16(const AT* __restrict__ A,
                                                     const _Float16* __restrict__ Bt,
                                                     const float* __restrict__ dinv,
                                                     _Float16* __restrict__ C) {
    constexpr bool AF32 = std::is_same<AT, float>::value;
    constexpr int FC = M / 16;
    constexpr int NIT = K / 32;
    const int tid = threadIdx.x;
    const int wave = tid >> 6, lane = tid & 63;
    const int row0 = blockIdx.x * 64;
    const int r0 = wave * 16;
    const int l15 = lane & 15, kof = (lane >> 4) * 8;

    f32x4 acc[FC] = {};
    int g0 = row0 + r0 + l15;
    const int gr = (g0 < N_NODES) ? g0 : N_NODES - 1;

    f32x4 a_cur32[2], a_nxt32[2];
    f16x8 a_cur16, a_nxt16;
    f16x8 b_cur[FC], b_nxt[FC];

    {
        const AT* ap = A + (size_t)gr * K + kof;
        if constexpr (AF32) {
            a_cur32[0] = *(const f32x4*)ap;
            a_cur32[1] = *(const f32x4*)(ap + 4);
        } else {
            a_cur16 = *(const f16x8*)ap;
        }
    }
    #pragma unroll
    for (int c = 0; c < FC; ++c)
        b_cur[c] = *(const f16x8*)(Bt + (size_t)(c * 16 + l15) * K + kof);

    #pragma unroll
    for (int it = 0; it < NIT; ++it) {
        const int k1 = (it + 1) * 32;
        if (it + 1 < NIT) {
            const AT* ap = A + (size_t)gr * K + k1 + kof;
            if constexpr (AF32) {
                a_nxt32[0] = *(const f32x4*)ap;
                a_nxt32[1] = *(const f32x4*)(ap + 4);
            } else {
                a_nxt16 = *(const f16x8*)ap;
            }
            #pragma unroll
            for (int c = 0; c < FC; ++c)
                b_nxt[c] = *(const f16x8*)(Bt + (size_t)(c * 16 + l15) * K + k1 + kof);
        }
        f16x8 af;
        if constexpr (AF32) {
            #pragma unroll
            for (int j = 0; j < 4; ++j) {
                af[j] = (_Float16)a_cur32[0][j];
                af[4 + j] = (_Float16)a_cur32[1][j];
            }
        } else {
            af = a_cur16;
        }
        #pragma unroll
        for (int c = 0; c < FC; ++c)
            acc[c] = __builtin_amdgcn_mfma_f32_16x16x32_f16(af, b_cur[c], acc[c], 0, 0, 0);
        if (it + 1 < NIT) {
            if constexpr (AF32) {
                a_cur32[0] = a_nxt32[0];
                a_cur32[1] = a_nxt32[1];
            } else {
                a_cur16 = a_nxt16;
            }
            #pragma unroll
            for (int c = 0; c < FC; ++c) b_cur[c] = b_nxt[c];
        }
    }

    // ---- epilogue: C/D frag layout col=lane&15, row=(lane>>4)*4+reg; fp16 store ----
    #pragma unroll
    for (int j = 0; j < 4; ++j) {
        int g = row0 + r0 + (lane >> 4) * 4 + j;
        if (g >= N_NODES) continue;
        float s = dinv[g];
        #pragma unroll
        for (int c = 0; c < FC; ++c)
            C[(size_t)g * M + c * 16 + l15] = (_Float16)(acc[c][j] * s);
    }
}

// ---------------- CSR gather: out16[n] = fp16( dinv[n]*(sum hs[src] + hs[n]) + b ) ----------------
template<int M, int G>
__global__ __launch_bounds__(256) void gather_kernel(const int* __restrict__ rowptr,
                                                     const int* __restrict__ esorted,
                                                     const float* __restrict__ dinv,
                                                     const f16x8* __restrict__ hs,
                                                     const float* __restrict__ bias,
                                                     _Float16* __restrict__ out) {
    static_assert(M == 8 * G, "layout");
    constexpr int R = M / 8;   // f16x8 chunks per row
    int gid = blockIdx.x * blockDim.x + threadIdx.x;
    int node = gid / G;
    int lane = gid % G;
    if (node >= N_NODES) return;
    int beg = rowptr[node], end = rowptr[node + 1];
    float dn = dinv[node];
    f16x8 hv = hs[(size_t)node * R + lane];   // self term
    float acc[8];
    #pragma unroll
    for (int d = 0; d < 8; ++d) acc[d] = (float)hv[d];
    int j = beg;
    for (; j + 8 <= end; j += 8) {
        int s[8];
        f16x8 v[8];
        #pragma unroll
        for (int k = 0; k < 8; ++k) s[k] = esorted[j + k];
        #pragma unroll
        for (int k = 0; k < 8; ++k) v[k] = hs[(size_t)s[k] * R + lane];
        #pragma unroll
        for (int k = 0; k < 8; ++k)
            #pragma unroll
            for (int d = 0; d < 8; ++d) acc[d] += (float)v[k][d];
    }
    for (; j < end; ++j) {
        f16x8 v = hs[(size_t)esorted[j] * R + lane];
        #pragma unroll
        for (int d = 0; d < 8; ++d) acc[d] += (float)v[d];
    }
    const float* bp = bias + lane * 8;
    f16x8 o;
    #pragma unroll
    for (int d = 0; d < 8; ++d) o[d] = (_Float16)(acc[d] * dn + bp[d]);
    *((f16x8*)out + (size_t)node * R + lane) = o;
}

// ---------------- layer-2 gather fused with log_softmax (M=32, G=8), fp32 out ----------------
__global__ __launch_bounds__(256) void gather_lsm_kernel(const int* __restrict__ rowptr,
                                                         const int* __restrict__ esorted,
                                                         const float* __restrict__ dinv,
                                                         const f16x4* __restrict__ hs,
                                                         const float* __restrict__ bias,
                                                         float* __restrict__ out) {
    constexpr int R = 8;   // f16x4 chunks per 32-wide row
    int gid = blockIdx.x * blockDim.x + threadIdx.x;
    int node = gid / 8;
    int lane = gid % 8;
    if (node >= N_NODES) return;
    int beg = rowptr[node], end = rowptr[node + 1];
    float dn = dinv[node];
    f16x4 hv = hs[(size_t)node * R + lane];
    float4 acc = make_float4((float)hv[0], (float)hv[1], (float)hv[2], (float)hv[3]);
    int j = beg;
    for (; j + 4 <= end; j += 4) {
        int s0 = esorted[j + 0];
        int s1 = esorted[j + 1];
        int s2 = esorted[j + 2];
        int s3 = esorted[j + 3];
        f16x4 v0 = hs[(size_t)s0 * R + lane];
        f16x4 v1 = hs[(size_t)s1 * R + lane];
        f16x4 v2 = hs[(size_t)s2 * R + lane];
        f16x4 v3 = hs[(size_t)s3 * R + lane];
        acc.x += ((float)v0[0] + (float)v1[0]) + ((float)v2[0] + (float)v3[0]);
        acc.y += ((float)v0[1] + (float)v1[1]) + ((float)v2[1] + (float)v3[1]);
        acc.z += ((float)v0[2] + (float)v1[2]) + ((float)v2[2] + (float)v3[2]);
        acc.w += ((float)v0[3] + (float)v1[3]) + ((float)v2[3] + (float)v3[3]);
    }
    for (; j < end; ++j) {
        f16x4 v = hs[(size_t)esorted[j] * R + lane];
        acc.x += (float)v[0];
        acc.y += (float)v[1];
        acc.z += (float)v[2];
        acc.w += (float)v[3];
    }
    float4 b = ((const float4*)bias)[lane];
    float4 o;
    o.x = acc.x * dn + b.x;
    o.y = acc.y * dn + b.y;
    o.z = acc.z * dn + b.z;
    o.w = acc.w * dn + b.w;
    // log_softmax over the 32-class row (8 lanes x 4)
    float m = fmaxf(fmaxf(o.x, o.y), fmaxf(o.z, o.w));
    m = fmaxf(m, __shfl_xor(m, 1, 8));
    m = fmaxf(m, __shfl_xor(m, 2, 8));
    m = fmaxf(m, __shfl_xor(m, 4, 8));
    float s = expf(o.x - m) + expf(o.y - m) + expf(o.z - m) + expf(o.w - m);
    s += __shfl_xor(s, 1, 8);
    s += __shfl_xor(s, 2, 8);
    s += __shfl_xor(s, 4, 8);
    float ls = m + logf(s);
    float4 r;
    r.x = o.x - ls; r.y = o.y - ls; r.z = o.z - ls; r.w = o.w - ls;
    ((float4*)out)[(size_t)node * R + lane] = r;
}

extern "C" void kernel_launch(void* const* d_in, const int* in_sizes, int n_in,
                              void* d_out, int out_size, void* d_ws, size_t ws_size,
                              hipStream_t stream) {
    const float* x  = (const float*)d_in[0];
    const int*   ei = (const int*)d_in[1];     // [2, E] int32
    const float* W0 = (const float*)d_in[2];
    const float* b0 = (const float*)d_in[3];
    const float* W1 = (const float*)d_in[4];
    const float* b1 = (const float*)d_in[5];
    const float* W2 = (const float*)d_in[6];
    const float* b2 = (const float*)d_in[7];
    float* out = (float*)d_out;

    char* ws = (char*)d_ws;
    float* dinv    = (float*)(ws + 0);                  // 400 KB
    int*   deg     = (int*)  (ws + (512 << 10));        // 400 KB (reused as cursor)
    int*   rowptr  = (int*)  (ws + (1 << 20));          // 400 KB + 4
    int*   bsums   = (int*)  (ws + (1536 << 10));       // ~1.6 KB
    int*   bcnt    = (int*)  (ws + (1600 << 10));       // 25 KB (per-block slice counts)
    int*   esorted = (int*)  (ws + (2 << 20));          // 6.4 MB
    _Float16* Wt0  = (_Float16*)(ws + 8847360);             // 64 KB
    _Float16* Wt1  = (_Float16*)(ws + 8847360 + 65536);     // 32 KB
    _Float16* Wt2  = (_Float16*)(ws + 8847360 + 98304);     // 8 KB
    _Float16* hs     = (_Float16*)(ws + 9437184);              // 25.6 MB (fp16 h*dinv)
    _Float16* bufB16 = (_Float16*)(ws + 9437184 + 51200000);   // 25.6 MB (fp16 activations)
    int2*  epart   = (int2*) (ws + 86237184);           // 12.8 MB (NBLK x 2048 x int2)
    const int* esrc = ei;
    const int* edst = ei + N_EDGES;

    const int NB = (N_NODES + 255) / 256;   // 391

    // ---- degree / dinv / CSR (deterministic two-phase fill) / W pre-convert ----
    (void)hipMemsetAsync(deg, 0, N_NODES * sizeof(int), stream);
    count_deg_kernel<<<N_EDGES / 256, 256, 0, stream>>>(edst, deg);
    dinv_kernel<<<NB, 256, 0, stream>>>(deg, dinv);
    block_scan_kernel<<<NB, 256, 0, stream>>>(deg, rowptr, bsums);
    scan_bsums_kernel<<<1, 512, 0, stream>>>(bsums, NB);
    add_offsets_kernel<<<NB, 256, 0, stream>>>(rowptr, bsums, deg /*cursor*/);
    part_kernel<<<NBLK, 256, 0, stream>>>(esrc, edst, epart, bcnt);
    fill3_kernel<<<((NBLK + 7) / 8) * 8, 256, 0, stream>>>(epart, bcnt, deg /*cursor*/, esorted);
    wconv_kernel<<<(256 * 128 + 255) / 256, 256, 0, stream>>>(W0, 256, 128, Wt0);
    wconv_kernel<<<(128 * 128 + 255) / 256, 256, 0, stream>>>(W1, 128, 128, Wt1);
    wconv_kernel<<<(128 * 32 + 255) / 256, 256, 0, stream>>>(W2, 128, 32, Wt2);

    const int RB64 = (N_NODES + 63) / 64;   // 1563

    // ---- layer 0: hs = fp16((x @ W0) * dinv) ; aggregate -> bufB16 (fp16) ----
    mfma_gemm_f16<256, 128, float><<<RB64, 256, 0, stream>>>(x, Wt0, dinv, hs);
    gather_kernel<128, 16><<<(N_NODES * 16 + 255) / 256, 256, 0, stream>>>(
        rowptr, esorted, dinv, (const f16x8*)hs, b0, bufB16);

    // ---- layer 1 (A in fp16) ----
    mfma_gemm_f16<128, 128, _Float16><<<RB64, 256, 0, stream>>>(bufB16, Wt1, dinv, hs);
    gather_kernel<128, 16><<<(N_NODES * 16 + 255) / 256, 256, 0, stream>>>(
        rowptr, esorted, dinv, (const f16x8*)hs, b1, bufB16);

    // ---- layer 2 (A in fp16): gather fused with log_softmax, writes d_out ----
    mfma_gemm_f16<128, 32, _Float16><<<RB64, 256, 0, stream>>>(bufB16, Wt2, dinv, hs);
    gather_lsm_kernel<<<(N_NODES * 8 + 255) / 256, 256, 0, stream>>>(
        rowptr, esorted, dinv, (const f16x4*)hs, b2, out);
}

// Round 15
// 395.743 us; speedup vs baseline: 6.8301x; 1.0985x over previous
//
#include <hip/hip_runtime.h>
#include <hip/hip_bf16.h>
#include <type_traits>

#define N_NODES 100000
#define N_EDGES 1600000
#define SLICE_N 12500   // N_NODES / 8 dst-slices for XCD-local fill
#define NBLK    782     // ceil(N_EDGES / 2048)

typedef float f32x4 __attribute__((ext_vector_type(4)));
typedef _Float16 f16x8 __attribute__((ext_vector_type(8)));
typedef _Float16 f16x4 __attribute__((ext_vector_type(4)));

// ---------------- degree count (in-degree at dst) ----------------
__global__ void count_deg_kernel(const int* __restrict__ dst, int* __restrict__ deg) {
    int i = blockIdx.x * blockDim.x + threadIdx.x;
    if (i < N_EDGES) atomicAdd(&deg[dst[i]], 1);
}

__global__ void dinv_kernel(const int* __restrict__ deg, float* __restrict__ dinv) {
    int i = blockIdx.x * blockDim.x + threadIdx.x;
    if (i < N_NODES) dinv[i] = 1.0f / sqrtf((float)deg[i] + 1.0f);
}

// ---------------- CSR build: block scan -> partial scan -> add ----------------
__global__ void block_scan_kernel(const int* __restrict__ deg, int* __restrict__ rowptr,
                                  int* __restrict__ bsums) {
    __shared__ int s[256];
    int i = blockIdx.x * 256 + threadIdx.x;
    int v = (i < N_NODES) ? deg[i] : 0;
    s[threadIdx.x] = v;
    __syncthreads();
    #pragma unroll
    for (int off = 1; off < 256; off <<= 1) {
        int t = (threadIdx.x >= off) ? s[threadIdx.x - off] : 0;
        __syncthreads();
        s[threadIdx.x] += t;
        __syncthreads();
    }
    if (i < N_NODES) rowptr[i] = s[threadIdx.x] - v;   // exclusive within block
    if (threadIdx.x == 255) bsums[blockIdx.x] = s[255];
}

__global__ void scan_bsums_kernel(int* __restrict__ bsums, int nB) {
    __shared__ int s[512];
    int tid = threadIdx.x;
    int v = (tid < nB) ? bsums[tid] : 0;
    s[tid] = v;
    __syncthreads();
    #pragma unroll
    for (int off = 1; off < 512; off <<= 1) {
        int t = (tid >= off) ? s[tid - off] : 0;
        __syncthreads();
        s[tid] += t;
        __syncthreads();
    }
    if (tid < nB) bsums[tid] = s[tid] - v;             // exclusive
}

__global__ void add_offsets_kernel(int* __restrict__ rowptr, const int* __restrict__ bsums,
                                   int* __restrict__ cursor) {
    int i = blockIdx.x * 256 + threadIdx.x;
    if (i < N_NODES) {
        int r = rowptr[i] + bsums[blockIdx.x];
        rowptr[i] = r;
        cursor[i] = r;
    }
    if (i == 0) rowptr[N_NODES] = N_EDGES;
}

// ---- phase A: per-block slice-sort into private epart segment (NO global atomics) ----
__global__ __launch_bounds__(256) void part_kernel(const int* __restrict__ esrc,
                                                   const int* __restrict__ edst,
                                                   int2* __restrict__ epart,
                                                   int* __restrict__ bcnt) {
    __shared__ int hist[8];
    __shared__ int scan[8];
    __shared__ int2 stage[2048];
    const int blk = blockIdx.x;
    const int base = blk * 2048;
    int sl[8], lpos[8], ss[8], dd[8];
    if (threadIdx.x < 8) hist[threadIdx.x] = 0;
    __syncthreads();
    #pragma unroll
    for (int i = 0; i < 8; ++i) {
        int e = base + i * 256 + threadIdx.x;
        if (e < N_EDGES) {
            dd[i] = edst[e];
            ss[i] = esrc[e];
            sl[i] = dd[i] / SLICE_N;
            lpos[i] = atomicAdd(&hist[sl[i]], 1);   // LDS atomic
        } else {
            sl[i] = -1;
        }
    }
    __syncthreads();
    if (threadIdx.x == 0) {
        int acc = 0;
        #pragma unroll
        for (int t = 0; t < 8; ++t) { scan[t] = acc; acc += hist[t]; }
    }
    if (threadIdx.x < 8) bcnt[blk * 8 + threadIdx.x] = hist[threadIdx.x];
    __syncthreads();
    #pragma unroll
    for (int i = 0; i < 8; ++i)
        if (sl[i] >= 0) stage[scan[sl[i]] + lpos[i]] = make_int2(ss[i], dd[i]);
    __syncthreads();
    const int total = scan[7] + hist[7];
    #pragma unroll
    for (int i = 0; i < 8; ++i) {
        int idx = i * 256 + threadIdx.x;
        if (idx < total) epart[(size_t)blk * 2048 + idx] = stage[idx];
    }
}

// ---- phase B: per-slice fill from slice-sorted segments into L2-resident window ----
__global__ __launch_bounds__(256) void fill3_kernel(const int2* __restrict__ epart,
                                                    const int* __restrict__ bcnt,
                                                    int* __restrict__ cursor,
                                                    int* __restrict__ esorted) {
    const int sl = blockIdx.x & 7;
    const int chunk = blockIdx.x >> 3;
    #pragma unroll
    for (int q = 0; q < 8; ++q) {
        const int sb = chunk * 8 + q;
        if (sb < NBLK) {
            int off = 0, len = 0;
            #pragma unroll
            for (int t = 0; t < 8; ++t) {
                int c = bcnt[sb * 8 + t];
                if (t < sl) off += c;
                if (t == sl) len = c;
            }
            const int2* seg = epart + (size_t)sb * 2048 + off;
            for (int idx = threadIdx.x; idx < len; idx += 256) {
                int2 p = seg[idx];
                int pos = atomicAdd(&cursor[p.y], 1);
                esorted[pos] = p.x;
            }
        }
    }
}

// ---------------- W[K][M] row-major -> Wt[M][K] transposed fp16 ----------------
__global__ void wconv_kernel(const float* __restrict__ W, int K, int M,
                             _Float16* __restrict__ Wt) {
    int i = blockIdx.x * 256 + threadIdx.x;
    if (i >= K * M) return;
    int k = i / M, col = i % M;
    Wt[col * K + k] = (_Float16)W[i];
}

// ---------------- MFMA GEMM: B staged in LDS (XOR-swizzled), grid-stride row tiles ----------------
// C[r,:] = fp16( (A @ W)[r,:] * dinv[r] ); A fp32 (converted in-register) or fp16.
// 4 waves x 32-row strips = 128-row tiles; B ds_read_b128 2-way-conflict-free.
template<int K, int M, typename AT>
__global__ __launch_bounds__(256) void mfma_gemm_lds(const AT* __restrict__ A,
                                                     const _Float16* __restrict__ Bt,
                                                     const float* __restrict__ dinv,
                                                     _Float16* __restrict__ C,
                                                     int nTiles) {
    constexpr bool AF32 = std::is_same<AT, float>::value;
    constexpr int FC = M / 16;
    constexpr int NIT = K / 32;
    __shared__ _Float16 Bs[M * K];   // [col][k], 8-elem chunks XOR-swizzled by col&7
    const int tid = threadIdx.x;
    const int wave = tid >> 6, lane = tid & 63;
    const int l15 = lane & 15, kq = lane >> 4;
    const int kof = kq * 8;

    // ---- stage B once per block (coalesced 16B chunks, swizzled placement) ----
    #pragma unroll
    for (int i = tid; i < M * K / 8; i += 256) {
        int col = i / (K / 8);
        int kc = i % (K / 8);
        int pc = kc ^ (col & 7);
        *(f16x8*)&Bs[col * K + pc * 8] = *(const f16x8*)(Bt + (size_t)col * K + kc * 8);
    }
    __syncthreads();

    for (int tile = blockIdx.x; tile < nTiles; tile += gridDim.x) {
        const int rbase = tile * 128 + wave * 32;
        int gr[2];
        #pragma unroll
        for (int r = 0; r < 2; ++r) {
            int g = rbase + r * 16 + l15;
            gr[r] = (g < N_NODES) ? g : N_NODES - 1;
        }
        f32x4 acc[2][FC] = {};
        f32x4 a_cur32[2][2], a_nxt32[2][2];
        f16x8 a_cur16[2], a_nxt16[2];
        #pragma unroll
        for (int r = 0; r < 2; ++r) {
            const AT* ap = A + (size_t)gr[r] * K + kof;
            if constexpr (AF32) {
                a_cur32[r][0] = *(const f32x4*)ap;
                a_cur32[r][1] = *(const f32x4*)(ap + 4);
            } else {
                a_cur16[r] = *(const f16x8*)ap;
            }
        }
        #pragma unroll
        for (int it = 0; it < NIT; ++it) {
            if (it + 1 < NIT) {
                const int k1 = (it + 1) * 32;
                #pragma unroll
                for (int r = 0; r < 2; ++r) {
                    const AT* ap = A + (size_t)gr[r] * K + k1 + kof;
                    if constexpr (AF32) {
                        a_nxt32[r][0] = *(const f32x4*)ap;
                        a_nxt32[r][1] = *(const f32x4*)(ap + 4);
                    } else {
                        a_nxt16[r] = *(const f16x8*)ap;
                    }
                }
            }
            f16x8 af[2];
            #pragma unroll
            for (int r = 0; r < 2; ++r) {
                if constexpr (AF32) {
                    #pragma unroll
                    for (int j = 0; j < 4; ++j) {
                        af[r][j] = (_Float16)a_cur32[r][0][j];
                        af[r][4 + j] = (_Float16)a_cur32[r][1][j];
                    }
                } else {
                    af[r] = a_cur16[r];
                }
            }
            const int kc = it * 4 + kq;
            #pragma unroll
            for (int c = 0; c < FC; ++c) {
                int col = c * 16 + l15;
                f16x8 bh = *(const f16x8*)&Bs[col * K + (kc ^ (l15 & 7)) * 8];
                #pragma unroll
                for (int r = 0; r < 2; ++r)
                    acc[r][c] = __builtin_amdgcn_mfma_f32_16x16x32_f16(af[r], bh, acc[r][c], 0, 0, 0);
            }
            if (it + 1 < NIT) {
                #pragma unroll
                for (int r = 0; r < 2; ++r) {
                    if constexpr (AF32) {
                        a_cur32[r][0] = a_nxt32[r][0];
                        a_cur32[r][1] = a_nxt32[r][1];
                    } else {
                        a_cur16[r] = a_nxt16[r];
                    }
                }
            }
        }
        // ---- epilogue: C/D frag layout col=lane&15, row=(lane>>4)*4+reg; fp16 store ----
        #pragma unroll
        for (int r = 0; r < 2; ++r) {
            #pragma unroll
            for (int j = 0; j < 4; ++j) {
                int g = rbase + r * 16 + kq * 4 + j;
                if (g >= N_NODES) continue;
                float s = dinv[g];
                #pragma unroll
                for (int c = 0; c < FC; ++c)
                    C[(size_t)g * M + c * 16 + l15] = (_Float16)(acc[r][c][j] * s);
            }
        }
    }
}

// ---------------- CSR gather: out16[n] = fp16( dinv[n]*(sum hs[src] + hs[n]) + b ) ----------------
template<int M, int G>
__global__ __launch_bounds__(256) void gather_kernel(const int* __restrict__ rowptr,
                                                     const int* __restrict__ esorted,
                                                     const float* __restrict__ dinv,
                                                     const f16x8* __restrict__ hs,
                                                     const float* __restrict__ bias,
                                                     _Float16* __restrict__ out) {
    static_assert(M == 8 * G, "layout");
    constexpr int R = M / 8;   // f16x8 chunks per row
    int gid = blockIdx.x * blockDim.x + threadIdx.x;
    int node = gid / G;
    int lane = gid % G;
    if (node >= N_NODES) return;
    int beg = rowptr[node], end = rowptr[node + 1];
    float dn = dinv[node];
    f16x8 hv = hs[(size_t)node * R + lane];   // self term
    float acc[8];
    #pragma unroll
    for (int d = 0; d < 8; ++d) acc[d] = (float)hv[d];
    int j = beg;
    for (; j + 8 <= end; j += 8) {
        int s[8];
        f16x8 v[8];
        #pragma unroll
        for (int k = 0; k < 8; ++k) s[k] = esorted[j + k];
        #pragma unroll
        for (int k = 0; k < 8; ++k) v[k] = hs[(size_t)s[k] * R + lane];
        #pragma unroll
        for (int k = 0; k < 8; ++k)
            #pragma unroll
            for (int d = 0; d < 8; ++d) acc[d] += (float)v[k][d];
    }
    for (; j < end; ++j) {
        f16x8 v = hs[(size_t)esorted[j] * R + lane];
        #pragma unroll
        for (int d = 0; d < 8; ++d) acc[d] += (float)v[d];
    }
    const float* bp = bias + lane * 8;
    f16x8 o;
    #pragma unroll
    for (int d = 0; d < 8; ++d) o[d] = (_Float16)(acc[d] * dn + bp[d]);
    *((f16x8*)out + (size_t)node * R + lane) = o;
}

// ---------------- layer-2 gather fused with log_softmax (M=32, G=8), fp32 out ----------------
__global__ __launch_bounds__(256) void gather_lsm_kernel(const int* __restrict__ rowptr,
                                                         const int* __restrict__ esorted,
                                                         const float* __restrict__ dinv,
                                                         const f16x4* __restrict__ hs,
                                                         const float* __restrict__ bias,
                                                         float* __restrict__ out) {
    constexpr int R = 8;   // f16x4 chunks per 32-wide row
    int gid = blockIdx.x * blockDim.x + threadIdx.x;
    int node = gid / 8;
    int lane = gid % 8;
    if (node >= N_NODES) return;
    int beg = rowptr[node], end = rowptr[node + 1];
    float dn = dinv[node];
    f16x4 hv = hs[(size_t)node * R + lane];
    float4 acc = make_float4((float)hv[0], (float)hv[1], (float)hv[2], (float)hv[3]);
    int j = beg;
    for (; j + 4 <= end; j += 4) {
        int s0 = esorted[j + 0];
        int s1 = esorted[j + 1];
        int s2 = esorted[j + 2];
        int s3 = esorted[j + 3];
        f16x4 v0 = hs[(size_t)s0 * R + lane];
        f16x4 v1 = hs[(size_t)s1 * R + lane];
        f16x4 v2 = hs[(size_t)s2 * R + lane];
        f16x4 v3 = hs[(size_t)s3 * R + lane];
        acc.x += ((float)v0[0] + (float)v1[0]) + ((float)v2[0] + (float)v3[0]);
        acc.y += ((float)v0[1] + (float)v1[1]) + ((float)v2[1] + (float)v3[1]);
        acc.z += ((float)v0[2] + (float)v1[2]) + ((float)v2[2] + (float)v3[2]);
        acc.w += ((float)v0[3] + (float)v1[3]) + ((float)v2[3] + (float)v3[3]);
    }
    for (; j < end; ++j) {
        f16x4 v = hs[(size_t)esorted[j] * R + lane];
        acc.x += (float)v[0];
        acc.y += (float)v[1];
        acc.z += (float)v[2];
        acc.w += (float)v[3];
    }
    float4 b = ((const float4*)bias)[lane];
    float4 o;
    o.x = acc.x * dn + b.x;
    o.y = acc.y * dn + b.y;
    o.z = acc.z * dn + b.z;
    o.w = acc.w * dn + b.w;
    // log_softmax over the 32-class row (8 lanes x 4)
    float m = fmaxf(fmaxf(o.x, o.y), fmaxf(o.z, o.w));
    m = fmaxf(m, __shfl_xor(m, 1, 8));
    m = fmaxf(m, __shfl_xor(m, 2, 8));
    m = fmaxf(m, __shfl_xor(m, 4, 8));
    float s = expf(o.x - m) + expf(o.y - m) + expf(o.z - m) + expf(o.w - m);
    s += __shfl_xor(s, 1, 8);
    s += __shfl_xor(s, 2, 8);
    s += __shfl_xor(s, 4, 8);
    float ls = m + logf(s);
    float4 r;
    r.x = o.x - ls; r.y = o.y - ls; r.z = o.z - ls; r.w = o.w - ls;
    ((float4*)out)[(size_t)node * R + lane] = r;
}

extern "C" void kernel_launch(void* const* d_in, const int* in_sizes, int n_in,
                              void* d_out, int out_size, void* d_ws, size_t ws_size,
                              hipStream_t stream) {
    const float* x  = (const float*)d_in[0];
    const int*   ei = (const int*)d_in[1];     // [2, E] int32
    const float* W0 = (const float*)d_in[2];
    const float* b0 = (const float*)d_in[3];
    const float* W1 = (const float*)d_in[4];
    const float* b1 = (const float*)d_in[5];
    const float* W2 = (const float*)d_in[6];
    const float* b2 = (const float*)d_in[7];
    float* out = (float*)d_out;

    char* ws = (char*)d_ws;
    float* dinv    = (float*)(ws + 0);                  // 400 KB
    int*   deg     = (int*)  (ws + (512 << 10));        // 400 KB (reused as cursor)
    int*   rowptr  = (int*)  (ws + (1 << 20));          // 400 KB + 4
    int*   bsums   = (int*)  (ws + (1536 << 10));       // ~1.6 KB
    int*   bcnt    = (int*)  (ws + (1600 << 10));       // 25 KB (per-block slice counts)
    int*   esorted = (int*)  (ws + (2 << 20));          // 6.4 MB
    _Float16* Wt0  = (_Float16*)(ws + 8847360);             // 64 KB
    _Float16* Wt1  = (_Float16*)(ws + 8847360 + 65536);     // 32 KB
    _Float16* Wt2  = (_Float16*)(ws + 8847360 + 98304);     // 8 KB
    _Float16* hs     = (_Float16*)(ws + 9437184);              // 25.6 MB (fp16 h*dinv)
    _Float16* bufB16 = (_Float16*)(ws + 9437184 + 51200000);   // 25.6 MB (fp16 activations)
    int2*  epart   = (int2*) (ws + 86237184);           // 12.8 MB (NBLK x 2048 x int2)
    const int* esrc = ei;
    const int* edst = ei + N_EDGES;

    const int NB = (N_NODES + 255) / 256;   // 391

    // ---- degree / dinv / CSR (deterministic two-phase fill) / W pre-convert ----
    (void)hipMemsetAsync(deg, 0, N_NODES * sizeof(int), stream);
    count_deg_kernel<<<N_EDGES / 256, 256, 0, stream>>>(edst, deg);
    dinv_kernel<<<NB, 256, 0, stream>>>(deg, dinv);
    block_scan_kernel<<<NB, 256, 0, stream>>>(deg, rowptr, bsums);
    scan_bsums_kernel<<<1, 512, 0, stream>>>(bsums, NB);
    add_offsets_kernel<<<NB, 256, 0, stream>>>(rowptr, bsums, deg /*cursor*/);
    part_kernel<<<NBLK, 256, 0, stream>>>(esrc, edst, epart, bcnt);
    fill3_kernel<<<((NBLK + 7) / 8) * 8, 256, 0, stream>>>(epart, bcnt, deg /*cursor*/, esorted);
    wconv_kernel<<<(256 * 128 + 255) / 256, 256, 0, stream>>>(W0, 256, 128, Wt0);
    wconv_kernel<<<(128 * 128 + 255) / 256, 256, 0, stream>>>(W1, 128, 128, Wt1);
    wconv_kernel<<<(128 * 32 + 255) / 256, 256, 0, stream>>>(W2, 128, 32, Wt2);

    const int NT = (N_NODES + 127) / 128;   // 782 row tiles

    // ---- layer 0: hs = fp16((x @ W0) * dinv) ; aggregate -> bufB16 (fp16) ----
    mfma_gemm_lds<256, 128, float><<<512, 256, 0, stream>>>(x, Wt0, dinv, hs, NT);
    gather_kernel<128, 16><<<(N_NODES * 16 + 255) / 256, 256, 0, stream>>>(
        rowptr, esorted, dinv, (const f16x8*)hs, b0, bufB16);

    // ---- layer 1 (A in fp16) ----
    mfma_gemm_lds<128, 128, _Float16><<<NT, 256, 0, stream>>>(bufB16, Wt1, dinv, hs, NT);
    gather_kernel<128, 16><<<(N_NODES * 16 + 255) / 256, 256, 0, stream>>>(
        rowptr, esorted, dinv, (const f16x8*)hs, b1, bufB16);

    // ---- layer 2 (A in fp16): gather fused with log_softmax, writes d_out ----
    mfma_gemm_lds<128, 32, _Float16><<<NT, 256, 0, stream>>>(bufB16, Wt2, dinv, hs, NT);
    gather_lsm_kernel<<<(N_NODES * 8 + 255) / 256, 256, 0, stream>>>(
        rowptr, esorted, dinv, (const f16x4*)hs, b2, out);
}